// Round 1
// baseline (495.346 us; speedup 1.0000x reference)
//
#include <hip/hip_runtime.h>
#include <stdint.h>

// MRICls fused kernel for MI355X (gfx950).
// B=131072 rows. feat = [F0*g, F1*g, S0*g, S1*g] (464) -> 64 -> 32 -> 2 -> softmax.
// g = sigmoid(0.25*(F0+F1)*(S0+S1)) per (row, j<116).
// Layer 1 via split-bf16 MFMA (hi/lo, 3 products) == fp32 accuracy.
// ws usage: 15 chunks * 10240 B = 153600 B (bf16 hi/lo of W1, transposed, k-padded).

typedef float  f4    __attribute__((ext_vector_type(4)));
typedef float  f32x4 __attribute__((ext_vector_type(4)));
typedef short  s8    __attribute__((ext_vector_type(8)));

#define NSTEP 15   // K = 15*32 = 480 (464 real + 16 pad)

__device__ __forceinline__ unsigned short f2bf(float x) {
  uint32_t u = __float_as_uint(x);
  return (unsigned short)((u + 0x7FFFu + ((u >> 16) & 1u)) >> 16);  // RNE
}
__device__ __forceinline__ float bf2f(unsigned short b) {
  return __uint_as_float(((uint32_t)b) << 16);
}

// ---- prep: split W1 (464x64 fp32) into bf16 hi/lo chunks in ws ----
// ws chunk t (t<15): shorts [plane 2][n 64][kk 40]; kk<32 real (k=32t+kk), kk>=32 pad.
__global__ void prep_w1(const float* __restrict__ W1, short* __restrict__ Wsp) {
  int e  = blockIdx.x * 256 + threadIdx.x;   // 0..30719
  int t  = e >> 11;
  int r  = e & 2047;
  int n  = r & 63;        // n fastest -> coalesced W1 reads
  int kk = r >> 6;        // 0..31
  int k  = t * 32 + kk;
  float v = (k < 464) ? W1[k * 64 + n] : 0.f;
  unsigned short hi = f2bf(v);
  unsigned short lo = f2bf(v - bf2f(hi));
  Wsp[t * 5120 +        n * 40 + kk] = (short)hi;
  Wsp[t * 5120 + 2560 + n * 40 + kk] = (short)lo;
}

__device__ __forceinline__ void ld5(uint64_t r[5], const uint64_t* src, int tid) {
#pragma unroll
  for (int i = 0; i < 5; ++i) r[i] = src[tid + i * 256];
}
__device__ __forceinline__ void st5(uint64_t* dst, const uint64_t r[5], int tid) {
#pragma unroll
  for (int i = 0; i < 5; ++i) dst[tid + i * 256] = r[i];
}

__global__ __launch_bounds__(256, 2) void mricls_main(
    const float* __restrict__ F, const float* __restrict__ S,
    const float* __restrict__ b1, const float* __restrict__ W2,
    const float* __restrict__ b2, const float* __restrict__ W3,
    const float* __restrict__ b3, const short* __restrict__ Wsp,
    float* __restrict__ out) {
  // Region A (30720 B), time-multiplexed: F/S sums -> g ; then W1 double-buf ; then h1.
  __shared__ __align__(16) union {
    float    tmp[64][120];     // 30720 B
    uint64_t wbuf[2][1280];    // 20480 B (two 10240 B chunks: [plane][n][40] shorts)
    float    h1[64][68];       // 17408 B
  } A;
  __shared__ __align__(16) float W2s[64][32];
  __shared__ float W3s[32][2];
  __shared__ float b1s[64];
  __shared__ float b2s[32];
  __shared__ float b3s[2];

  const int tid  = threadIdx.x;
  const int l    = tid & 63;
  const int w    = tid >> 6;      // wave 0..3
  const int ml   = l & 15;        // MFMA A-row / B-col lane bits
  const int h    = l >> 4;        // k-slice group (8 contiguous k's)
  const int mloc = w * 16 + ml;   // row within block tile (0..63)
  const long row = (long)blockIdx.x * 64 + mloc;
  const float* Fr = F + row * 232;
  const float* Sr = S + row * 232;

  // ---- upfront global loads: this lane's A-slices (each HBM byte read once) ----
  f4 raw[NSTEP][2];
#pragma unroll
  for (int t = 0; t < NSTEP; ++t) {
#pragma unroll
    for (int c = 0; c < 2; ++c) {
      const int kk = 32 * t + 8 * h + 4 * c;
      const float* p = (kk < 232) ? (Fr + kk) : ((kk < 464) ? (Sr + (kk - 232)) : Fr);
      f4 v = *(const f4*)p;
      if (kk >= 464) v = (f4){0.f, 0.f, 0.f, 0.f};
      raw[t][c] = v;
    }
  }

  // ---- prefetch W1 chunks 0,1 into regs (L2-hot after first blocks) ----
  const uint64_t* ws64 = (const uint64_t*)Wsp;
  uint64_t ca[5], cb[5];
  ld5(ca, ws64, tid);           // chunk 0 (even -> ca)
  ld5(cb, ws64 + 1280, tid);    // chunk 1 (odd  -> cb)

  // ---- small weights to LDS (region C) ----
  {
    const f4* W2v = (const f4*)W2;
    f4* W2sv = (f4*)W2s;
#pragma unroll
    for (int i = 0; i < 2; ++i) W2sv[tid + 256 * i] = W2v[tid + 256 * i];
    if (tid < 16) ((f4*)W3s)[tid] = ((const f4*)W3)[tid];
    if (tid < 16) ((f4*)b1s)[tid] = ((const f4*)b1)[tid];
    if (tid < 8)  ((f4*)b2s)[tid] = ((const f4*)b2)[tid];
    if (tid < 2)  b3s[tid] = b3[tid];
  }

  // ---- phase 0: quarter-staged gate computation ----
  const int gm  = tid & 63;
  const int gj0 = (tid >> 6) * 29;
  float mF[29];

  // Q0: kk in [0,116) -> tmp[m][kk] = F0
#pragma unroll
  for (int t = 0; t <= 3; ++t)
#pragma unroll
    for (int c = 0; c < 2; ++c) {
      const int kk = 32 * t + 8 * h + 4 * c;
      if (kk < 116) *(f4*)&A.tmp[mloc][kk] = raw[t][c];
    }
  __syncthreads();
  // Q1: kk in [116,232) -> tmp[m][kk-116] += F1
#pragma unroll
  for (int t = 3; t <= 7; ++t)
#pragma unroll
    for (int c = 0; c < 2; ++c) {
      const int kk = 32 * t + 8 * h + 4 * c;
      if (kk >= 116 && kk < 232) {
        const float* rp = (const float*)&raw[t][c];
#pragma unroll
        for (int e = 0; e < 4; ++e) atomicAdd(&A.tmp[mloc][kk - 116 + e], rp[e]);
      }
    }
  __syncthreads();
#pragma unroll
  for (int i = 0; i < 29; ++i) mF[i] = A.tmp[gm][gj0 + i];  // F0+F1
  __syncthreads();
  // Q2: kk in [232,348) -> tmp[m][kk-232] = S0
#pragma unroll
  for (int t = 7; t <= 10; ++t)
#pragma unroll
    for (int c = 0; c < 2; ++c) {
      const int kk = 32 * t + 8 * h + 4 * c;
      if (kk >= 232 && kk < 348) *(f4*)&A.tmp[mloc][kk - 232] = raw[t][c];
    }
  __syncthreads();
  // Q3: kk in [348,464) -> tmp[m][kk-348] += S1
#pragma unroll
  for (int t = 10; t <= 14; ++t)
#pragma unroll
    for (int c = 0; c < 2; ++c) {
      const int kk = 32 * t + 8 * h + 4 * c;
      if (kk >= 348 && kk < 464) {
        const float* rp = (const float*)&raw[t][c];
#pragma unroll
        for (int e = 0; e < 4; ++e) atomicAdd(&A.tmp[mloc][kk - 348 + e], rp[e]);
      }
    }
  __syncthreads();
  // g = sigmoid(0.25*(F0+F1)*(S0+S1)), in place (each thread owns its cells)
#pragma unroll
  for (int i = 0; i < 29; ++i) {
    float x  = 0.25f * mF[i] * A.tmp[gm][gj0 + i];
    float gg = 1.f / (1.f + __expf(-x));
    A.tmp[gm][gj0 + i] = gg;
  }
  __syncthreads();

  // ---- gate + split into bf16 hi/lo A-fragments ----
  s8 ahi[NSTEP], alo[NSTEP];
#pragma unroll
  for (int t = 0; t < NSTEP; ++t) {
    float fe[8];
#pragma unroll
    for (int c = 0; c < 2; ++c) {
      const int kk = 32 * t + 8 * h + 4 * c;
      const int qq = (kk >= 116) + (kk >= 232) + (kk >= 348);
      const int jj = kk - 116 * qq;
      f4 gv;
      if (kk < 464) gv = *(const f4*)&A.tmp[mloc][jj];
      else          gv = (f4){0.f, 0.f, 0.f, 0.f};
      const float* rp = (const float*)&raw[t][c];
      const float* gp = (const float*)&gv;
#pragma unroll
      for (int e = 0; e < 4; ++e) fe[c * 4 + e] = rp[e] * gp[e];
    }
#pragma unroll
    for (int e = 0; e < 8; ++e) {
      unsigned short hb = f2bf(fe[e]);
      float dd = fe[e] - bf2f(hb);
      unsigned short lb = f2bf(dd);
      ahi[t][e] = (short)hb;
      alo[t][e] = (short)lb;
    }
  }
  __syncthreads();  // tmp dead -> wbuf region live

  // ---- K-loop: 15 steps, double-buffered W1 chunks, 12 MFMA/step/wave ----
  f32x4 acc[4];
#pragma unroll
  for (int nt = 0; nt < 4; ++nt) acc[nt] = (f32x4){0.f, 0.f, 0.f, 0.f};

  st5(A.wbuf[0], ca, tid);        // chunk 0 -> buf0
  ld5(ca, ws64 + 2 * 1280, tid);  // refill ca with chunk 2
  __syncthreads();

#pragma unroll
  for (int t = 0; t < NSTEP; ++t) {
    if (t + 1 < NSTEP) {  // write chunk t+1 (loaded earlier), refill same reg set with t+3
      uint64_t* dst = A.wbuf[(t + 1) & 1];
      if ((t + 1) & 1) {
        st5(dst, cb, tid);
        if (t + 3 < NSTEP) ld5(cb, ws64 + (t + 3) * 1280, tid);
      } else {
        st5(dst, ca, tid);
        if (t + 3 < NSTEP) ld5(ca, ws64 + (t + 3) * 1280, tid);
      }
    }
    const short* base = (const short*)A.wbuf[t & 1];
#pragma unroll
    for (int nt = 0; nt < 4; ++nt) {
      const int n = nt * 16 + ml;
      s8 bhi = *(const s8*)(base +        n * 40 + 8 * h);
      s8 blo = *(const s8*)(base + 2560 + n * 40 + 8 * h);
      acc[nt] = __builtin_amdgcn_mfma_f32_16x16x32_bf16(ahi[t], bhi, acc[nt], 0, 0, 0);
      acc[nt] = __builtin_amdgcn_mfma_f32_16x16x32_bf16(ahi[t], blo, acc[nt], 0, 0, 0);
      acc[nt] = __builtin_amdgcn_mfma_f32_16x16x32_bf16(alo[t], bhi, acc[nt], 0, 0, 0);
    }
    __syncthreads();
  }

  // ---- epilogue: h1 = relu(acc + b1) -> LDS ----
#pragma unroll
  for (int nt = 0; nt < 4; ++nt) {
    const int n = nt * 16 + ml;
    const float bias = b1s[n];
#pragma unroll
    for (int r = 0; r < 4; ++r) {
      const int mm = w * 16 + h * 4 + r;  // C/D: col=lane&15, row=(lane>>4)*4+reg
      A.h1[mm][n] = fmaxf(acc[nt][r] + bias, 0.f);
    }
  }
  __syncthreads();

  // ---- layers 2,3 + softmax (fp32 VALU; 4 threads per row) ----
  const int m2 = tid >> 2;  // row 0..63
  const int q  = tid & 3;   // 8 h2-outputs each
  float acc2[8];
#pragma unroll
  for (int e = 0; e < 8; ++e) acc2[e] = b2s[q * 8 + e];
#pragma unroll 8
  for (int k = 0; k < 64; ++k) {
    const float hk = A.h1[m2][k];
    const f4 w0 = *(const f4*)&W2s[k][q * 8];
    const f4 w1 = *(const f4*)&W2s[k][q * 8 + 4];
    acc2[0] = fmaf(hk, w0[0], acc2[0]);
    acc2[1] = fmaf(hk, w0[1], acc2[1]);
    acc2[2] = fmaf(hk, w0[2], acc2[2]);
    acc2[3] = fmaf(hk, w0[3], acc2[3]);
    acc2[4] = fmaf(hk, w1[0], acc2[4]);
    acc2[5] = fmaf(hk, w1[1], acc2[5]);
    acc2[6] = fmaf(hk, w1[2], acc2[6]);
    acc2[7] = fmaf(hk, w1[3], acc2[7]);
  }
  float p0 = 0.f, p1 = 0.f;
#pragma unroll
  for (int e = 0; e < 8; ++e) {
    const float hv = fmaxf(acc2[e], 0.f);
    p0 = fmaf(hv, W3s[q * 8 + e][0], p0);
    p1 = fmaf(hv, W3s[q * 8 + e][1], p1);
  }
  p0 += __shfl_xor(p0, 1); p0 += __shfl_xor(p0, 2);
  p1 += __shfl_xor(p1, 1); p1 += __shfl_xor(p1, 2);
  if (q == 0) {
    const float l0 = p0 + b3s[0], l1 = p1 + b3s[1];
    const float mx = fmaxf(l0, l1);
    const float e0 = __expf(l0 - mx), e1 = __expf(l1 - mx);
    const float inv = 1.f / (e0 + e1);
    float2 o = make_float2(e0 * inv, e1 * inv);
    *(float2*)(out + ((long)blockIdx.x * 64 + m2) * 2) = o;
  }
}

extern "C" void kernel_launch(void* const* d_in, const int* in_sizes, int n_in,
                              void* d_out, int out_size, void* d_ws, size_t ws_size,
                              hipStream_t stream) {
  const float* F  = (const float*)d_in[0];
  const float* S  = (const float*)d_in[1];
  const float* W1 = (const float*)d_in[2];
  const float* b1 = (const float*)d_in[3];
  const float* W2 = (const float*)d_in[4];
  const float* b2 = (const float*)d_in[5];
  const float* W3 = (const float*)d_in[6];
  const float* b3 = (const float*)d_in[7];
  short* Wsp = (short*)d_ws;   // needs 153600 B
  float* out = (float*)d_out;
  const int B = in_sizes[0] / 232;  // 131072

  prep_w1<<<dim3(120), dim3(256), 0, stream>>>(W1, Wsp);
  mricls_main<<<dim3(B / 64), dim3(256), 0, stream>>>(F, S, b1, W2, b2, W3, b3,
                                                      (const short*)Wsp, out);
}

// Round 2
// 311.214 us; speedup vs baseline: 1.5917x; 1.5917x over previous
//
#include <hip/hip_runtime.h>
#include <stdint.h>

// MRICls fused kernel for MI355X (gfx950) — round 2.
// B=131072 rows. feat = [F0*g, F1*g, S0*g, S1*g] (464) -> 64 -> 32 -> 2 -> softmax.
// g = sigmoid(0.25*(F0+F1)*(S0+S1)) per (row, j<116) — elementwise in j, so each
// lane computes its own gate from 4 loads in the same row and produces the 4 gated
// feat entries (k = j, j+116, j+232, j+348) directly. Layer 1 in fp16 MFMA
// (single precision; h1 err ~1.3e-4 rms, softmax err ~2e-5 — far under tolerance).
// W1 prepped to fp16 fragment-direct layout in ws, read from global (L2-hot) each
// K-step: no K-loop barriers, no W-LDS.
// ws usage: 15*2048*2 = 61440 B.

typedef float     f4    __attribute__((ext_vector_type(4)));
typedef float     f32x4 __attribute__((ext_vector_type(4)));
typedef _Float16  h4    __attribute__((ext_vector_type(4)));
typedef _Float16  h8    __attribute__((ext_vector_type(8)));

#define NSTEP 15      // K = 15*32 = 480 (464 real + 16 zero-pad)
#define LDA   488     // A-tile row stride in fp16 elems: 976 B = 244 dwords = 20 mod 32 banks
                      // -> ds_read_b128 of 16 row-strided lanes hits the 8-cyc minimum (no conflict)

// ---- prep: W1 (464x64 fp32) -> fp16, fragment-direct [t][n 64][kk 32] ----
__global__ void prep_w1(const float* __restrict__ W1, _Float16* __restrict__ Wsp) {
  const int e  = blockIdx.x * 256 + threadIdx.x;  // 0..30719
  const int t  = e >> 11;
  const int r  = e & 2047;
  const int n  = r & 63;     // n fastest -> coalesced W1 reads
  const int kk = r >> 6;     // 0..31
  const int k  = t * 32 + kk;
  const float v = (k < 464) ? W1[k * 64 + n] : 0.f;
  Wsp[t * 2048 + n * 32 + kk] = (_Float16)v;
}

__global__ __launch_bounds__(256, 2) void mricls_main(
    const float* __restrict__ F, const float* __restrict__ S,
    const float* __restrict__ b1, const float* __restrict__ W2,
    const float* __restrict__ b2, const float* __restrict__ W3,
    const float* __restrict__ b3, const _Float16* __restrict__ Wsp,
    float* __restrict__ out) {
  // A-tile (62464 B) is dead after the K-loop; h1 reuses the space.
  __shared__ __align__(16) union {
    _Float16 A16[64 * LDA];   // 62464 B
    float    h1[64][68];      // 17408 B
  } U;
  __shared__ __align__(16) float W2s[64][32];
  __shared__ __align__(16) float W3s[32][2];
  __shared__ __align__(16) float b1s[64];
  __shared__ __align__(16) float b2s[32];
  __shared__ float b3s[2];

  const int tid = threadIdx.x;

  // ---- small weights to LDS ----
  {
    const f4* W2v = (const f4*)W2;
    f4* W2sv = (f4*)W2s;
#pragma unroll
    for (int i = 0; i < 2; ++i) W2sv[tid + 256 * i] = W2v[tid + 256 * i];
    if (tid < 16) ((f4*)W3s)[tid] = ((const f4*)W3)[tid];
    if (tid < 16) ((f4*)b1s)[tid] = ((const f4*)b1)[tid];
    if (tid < 8)  ((f4*)b2s)[tid] = ((const f4*)b2)[tid];
    if (tid < 2)  b3s[tid] = b3[tid];
  }

  // ---- zero the K-pad region of the A-tile (k 464..479); MFMA reads it ----
  {
    const int zr = tid >> 2;            // row 0..63
    const int zk = 464 + (tid & 3) * 4; // 464..476
    *(h4*)(U.A16 + zr * LDA + zk) = (h4){0, 0, 0, 0};
  }

  // ---- phase 1: stream F,S once (coalesced), per-lane gate, gated fp16 -> A-tile ----
  {
    const int  row = tid >> 2;   // 0..63
    const int  c   = tid & 3;
    const long grow = (long)blockIdx.x * 64 + row;
    const float* fr = F + grow * 232;
    const float* sr = S + grow * 232;
#pragma unroll
    for (int i = 0; i < 8; ++i) {
      const int q = c + 4 * i;   // 0..28 (c>0 skips i=7)
      if (q < 29) {
        const f4 f0 = *(const f4*)(fr + 4 * q);
        const f4 f1 = *(const f4*)(fr + 4 * q + 116);
        const f4 s0 = *(const f4*)(sr + 4 * q);
        const f4 s1 = *(const f4*)(sr + 4 * q + 116);
        h4 a0, a1, a2, a3;
#pragma unroll
        for (int e = 0; e < 4; ++e) {
          const float x = 0.25f * (f0[e] + f1[e]) * (s0[e] + s1[e]);
          const float g = 1.f / (1.f + __expf(-x));
          a0[e] = (_Float16)(f0[e] * g);
          a1[e] = (_Float16)(f1[e] * g);
          a2[e] = (_Float16)(s0[e] * g);
          a3[e] = (_Float16)(s1[e] * g);
        }
        _Float16* base = U.A16 + row * LDA + 4 * q;
        *(h4*)(base)       = a0;   // k = j
        *(h4*)(base + 116) = a1;   // k = 116 + j
        *(h4*)(base + 232) = a2;   // k = 232 + j
        *(h4*)(base + 348) = a3;   // k = 348 + j
      }
    }
  }
  __syncthreads();

  // ---- phase 2: K-loop, no barriers. A from LDS, B from global (L2-hot). ----
  const int l  = tid & 63;
  const int w  = tid >> 6;     // wave 0..3 -> rows w*16..w*16+15
  const int ml = l & 15;       // A row / B col lane bits
  const int h  = l >> 4;       // k-group (8 contiguous k)

  f32x4 acc[4];
#pragma unroll
  for (int nt = 0; nt < 4; ++nt) acc[nt] = (f32x4){0.f, 0.f, 0.f, 0.f};

  const _Float16* Arow  = U.A16 + (w * 16 + ml) * LDA + 8 * h;
  const _Float16* Bbase = Wsp + ml * 32 + 8 * h;
#pragma unroll
  for (int t = 0; t < NSTEP; ++t) {
    const h8 a = *(const h8*)(Arow + 32 * t);
#pragma unroll
    for (int nt = 0; nt < 4; ++nt) {
      const h8 b = *(const h8*)(Bbase + t * 2048 + nt * 512);  // [t][nt*16+ml][8h..]
      acc[nt] = __builtin_amdgcn_mfma_f32_16x16x32_f16(a, b, acc[nt], 0, 0, 0);
    }
  }
  __syncthreads();  // A-tile dead -> h1 region live

  // ---- epilogue: h1 = relu(acc + b1) -> LDS ----
#pragma unroll
  for (int nt = 0; nt < 4; ++nt) {
    const int n = nt * 16 + ml;
    const float bias = b1s[n];
#pragma unroll
    for (int r = 0; r < 4; ++r) {
      const int mm = w * 16 + h * 4 + r;  // C/D: col=lane&15, row=(lane>>4)*4+reg
      U.h1[mm][n] = fmaxf(acc[nt][r] + bias, 0.f);
    }
  }
  __syncthreads();

  // ---- layers 2,3 + softmax (fp32 VALU; 4 threads per row) ----
  const int m2 = tid >> 2;  // row 0..63
  const int q  = tid & 3;   // 8 h2-outputs each
  float acc2[8];
#pragma unroll
  for (int e = 0; e < 8; ++e) acc2[e] = b2s[q * 8 + e];
#pragma unroll 8
  for (int k = 0; k < 64; ++k) {
    const float hk = U.h1[m2][k];
    const f4 w0 = *(const f4*)&W2s[k][q * 8];
    const f4 w1 = *(const f4*)&W2s[k][q * 8 + 4];
    acc2[0] = fmaf(hk, w0[0], acc2[0]);
    acc2[1] = fmaf(hk, w0[1], acc2[1]);
    acc2[2] = fmaf(hk, w0[2], acc2[2]);
    acc2[3] = fmaf(hk, w0[3], acc2[3]);
    acc2[4] = fmaf(hk, w1[0], acc2[4]);
    acc2[5] = fmaf(hk, w1[1], acc2[5]);
    acc2[6] = fmaf(hk, w1[2], acc2[6]);
    acc2[7] = fmaf(hk, w1[3], acc2[7]);
  }
  float p0 = 0.f, p1 = 0.f;
#pragma unroll
  for (int e = 0; e < 8; ++e) {
    const float hv = fmaxf(acc2[e], 0.f);
    p0 = fmaf(hv, W3s[q * 8 + e][0], p0);
    p1 = fmaf(hv, W3s[q * 8 + e][1], p1);
  }
  p0 += __shfl_xor(p0, 1); p0 += __shfl_xor(p0, 2);
  p1 += __shfl_xor(p1, 1); p1 += __shfl_xor(p1, 2);
  if (q == 0) {
    const float l0 = p0 + b3s[0], l1 = p1 + b3s[1];
    const float mx = fmaxf(l0, l1);
    const float e0 = __expf(l0 - mx), e1 = __expf(l1 - mx);
    const float inv = 1.f / (e0 + e1);
    float2 o = make_float2(e0 * inv, e1 * inv);
    *(float2*)(out + ((long)blockIdx.x * 64 + m2) * 2) = o;
  }
}

extern "C" void kernel_launch(void* const* d_in, const int* in_sizes, int n_in,
                              void* d_out, int out_size, void* d_ws, size_t ws_size,
                              hipStream_t stream) {
  const float* F  = (const float*)d_in[0];
  const float* S  = (const float*)d_in[1];
  const float* W1 = (const float*)d_in[2];
  const float* b1 = (const float*)d_in[3];
  const float* W2 = (const float*)d_in[4];
  const float* b2 = (const float*)d_in[5];
  const float* W3 = (const float*)d_in[6];
  const float* b3 = (const float*)d_in[7];
  _Float16* Wsp = (_Float16*)d_ws;   // needs 61440 B
  float* out = (float*)d_out;
  const int B = in_sizes[0] / 232;   // 131072

  prep_w1<<<dim3(120), dim3(256), 0, stream>>>(W1, Wsp);
  mricls_main<<<dim3(B / 64), dim3(256), 0, stream>>>(F, S, b1, W2, b2, W3, b3,
                                                      (const _Float16*)Wsp, out);
}